// Round 1
// baseline (384.090 us; speedup 1.0000x reference)
//
#include <hip/hip_runtime.h>
#include <math.h>

#define B_ 256
#define M_ 3
#define L_ 100000
#define A_ 4096
#define H_ 512
#define MA_ (M_*A_)          // 12288
#define K1_ MA_
#define KC1_ 1024
#define NZ_ 12               // split-K chunks for GEMM1 (12*1024 = 12288)
#define BCHUNK_ 16           // b-values per block in fused kernel

static __device__ __forceinline__ float4 ld4(const float* p) {
    return *reinterpret_cast<const float4*>(p);
}
static __device__ __forceinline__ void st4(float* p, float4 v) {
    *reinterpret_cast<float4*>(p) = v;
}

__global__ void init_head(int* __restrict__ head) {
    int i = blockIdx.x * blockDim.x + threadIdx.x;
    if (i < L_) head[i] = -1;
}

__global__ void build_chain(const int* __restrict__ idx, int* __restrict__ head,
                            int* __restrict__ next) {
    int a = blockIdx.x * blockDim.x + threadIdx.x;
    if (a < A_) next[a] = atomicExch(&head[idx[a]], a);
}

// Fused: logits[b,l] = sum_m x[b,m,l]*(softmax(gl)[m]+dw[m,l]) + bias[l]
// and gather x_active[b, m*A+a] = x[b,m,idx[a]] using head/next chain map.
__global__ __launch_bounds__(256) void logits_gather(
    const float* __restrict__ x, const float* __restrict__ gl,
    const float* __restrict__ dw, const float* __restrict__ bias,
    const int* __restrict__ head, const int* __restrict__ next,
    float* __restrict__ logits, float* __restrict__ xa) {
    const int L4 = L_ / 4;
    int i = blockIdx.x * blockDim.x + threadIdx.x;
    if (i >= L4) return;
    int l = i * 4;
    int b0 = blockIdx.y * BCHUNK_;

    // softmax over 3 global logits (cheap, cached)
    float g0 = gl[0], g1 = gl[1], g2 = gl[2];
    float mx = fmaxf(g0, fmaxf(g1, g2));
    float e0 = expf(g0 - mx), e1 = expf(g1 - mx), e2 = expf(g2 - mx);
    float inv = 1.0f / (e0 + e1 + e2);
    float s0 = e0 * inv, s1 = e1 * inv, s2 = e2 * inv;

    float4 d0 = ld4(dw + l);
    float4 d1 = ld4(dw + L_ + l);
    float4 d2 = ld4(dw + 2 * L_ + l);
    float4 bb = ld4(bias + l);
    float4 w0 = make_float4(s0 + d0.x, s0 + d0.y, s0 + d0.z, s0 + d0.w);
    float4 w1 = make_float4(s1 + d1.x, s1 + d1.y, s1 + d1.z, s1 + d1.w);
    float4 w2 = make_float4(s2 + d2.x, s2 + d2.y, s2 + d2.z, s2 + d2.w);

    for (int b = b0; b < b0 + BCHUNK_; ++b) {
        const float* xb = x + (size_t)(b * M_) * L_;
        float4 x0 = ld4(xb + l);
        float4 x1 = ld4(xb + L_ + l);
        float4 x2 = ld4(xb + 2 * L_ + l);
        float4 o;
        o.x = x0.x * w0.x + x1.x * w1.x + x2.x * w2.x + bb.x;
        o.y = x0.y * w0.y + x1.y * w1.y + x2.y * w2.y + bb.y;
        o.z = x0.z * w0.z + x1.z * w1.z + x2.z * w2.z + bb.z;
        o.w = x0.w * w0.w + x1.w * w1.w + x2.w * w2.w + bb.w;
        st4(logits + (size_t)b * L_ + l, o);
    }

    // gather pass: rare (~16% of threads hit an active l)
    #pragma unroll
    for (int c = 0; c < 4; ++c) {
        int a = head[l + c];
        while (a >= 0) {
            for (int b = b0; b < b0 + BCHUNK_; ++b) {
                const float* xb = x + (size_t)(b * M_) * L_;
                float v0 = xb[l + c];
                float v1 = xb[L_ + l + c];
                float v2 = xb[2 * L_ + l + c];
                float* xab = xa + (size_t)b * MA_;
                xab[0 * A_ + a] = v0;
                xab[1 * A_ + a] = v1;
                xab[2 * A_ + a] = v2;
            }
            a = next[a];
        }
    }
}

// GEMM1 split-K: part[z,b,n] = sum_{k in chunk z} xa[b,k] * hw[n,k]
__global__ __launch_bounds__(256) void gemm1_splitk(
    const float* __restrict__ Xa, const float* __restrict__ W,
    float* __restrict__ part) {
    __shared__ float As[64][17];
    __shared__ float Bs[64][17];
    int tid = threadIdx.x;
    int tx = tid & 15, ty = tid >> 4;
    int row0 = blockIdx.x * 64;   // b
    int col0 = blockIdx.y * 64;   // n
    int k0 = blockIdx.z * KC1_;
    int lr = tid >> 2;            // 0..63
    int lk = (tid & 3) * 4;       // 0,4,8,12
    const float* pa = Xa + (size_t)(row0 + lr) * K1_ + k0 + lk;
    const float* pb = W + (size_t)(col0 + lr) * K1_ + k0 + lk;
    float acc[4][4] = {};
    for (int kt = 0; kt < KC1_; kt += 16) {
        float4 av = *reinterpret_cast<const float4*>(pa + kt);
        float4 bv = *reinterpret_cast<const float4*>(pb + kt);
        __syncthreads();
        As[lr][lk] = av.x; As[lr][lk + 1] = av.y; As[lr][lk + 2] = av.z; As[lr][lk + 3] = av.w;
        Bs[lr][lk] = bv.x; Bs[lr][lk + 1] = bv.y; Bs[lr][lk + 2] = bv.z; Bs[lr][lk + 3] = bv.w;
        __syncthreads();
        #pragma unroll
        for (int kk = 0; kk < 16; ++kk) {
            float a0 = As[ty * 4 + 0][kk], a1 = As[ty * 4 + 1][kk];
            float a2 = As[ty * 4 + 2][kk], a3 = As[ty * 4 + 3][kk];
            float b0 = Bs[tx * 4 + 0][kk], b1 = Bs[tx * 4 + 1][kk];
            float b2 = Bs[tx * 4 + 2][kk], b3 = Bs[tx * 4 + 3][kk];
            acc[0][0] += a0 * b0; acc[0][1] += a0 * b1; acc[0][2] += a0 * b2; acc[0][3] += a0 * b3;
            acc[1][0] += a1 * b0; acc[1][1] += a1 * b1; acc[1][2] += a1 * b2; acc[1][3] += a1 * b3;
            acc[2][0] += a2 * b0; acc[2][1] += a2 * b1; acc[2][2] += a2 * b2; acc[2][3] += a2 * b3;
            acc[3][0] += a3 * b0; acc[3][1] += a3 * b1; acc[3][2] += a3 * b2; acc[3][3] += a3 * b3;
        }
    }
    float* p = part + (size_t)(blockIdx.z * B_ + row0 + ty * 4) * H_ + col0 + tx * 4;
    #pragma unroll
    for (int i2 = 0; i2 < 4; ++i2) {
        float4 v = make_float4(acc[i2][0], acc[i2][1], acc[i2][2], acc[i2][3]);
        st4(p + (size_t)i2 * H_, v);
    }
}

// h[b,n] = relu(sum_z part[z,b,n] + hb[n])
__global__ void reduce_relu(const float* __restrict__ part,
                            const float* __restrict__ hb,
                            float* __restrict__ h) {
    int t = blockIdx.x * blockDim.x + threadIdx.x;
    if (t >= B_ * H_) return;
    int n = t & (H_ - 1);
    float s = hb[n];
    #pragma unroll
    for (int z = 0; z < NZ_; ++z) s += part[(size_t)z * B_ * H_ + t];
    h[t] = fmaxf(s, 0.0f);
}

// GEMM2: da[b,a] = sum_n h[b,n] * W2[a,n] + b2[a]   (K = 512)
__global__ __launch_bounds__(256) void gemm2(
    const float* __restrict__ Hm, const float* __restrict__ W2,
    const float* __restrict__ b2, float* __restrict__ da) {
    __shared__ float As[64][17];
    __shared__ float Bs[64][17];
    int tid = threadIdx.x;
    int tx = tid & 15, ty = tid >> 4;
    int row0 = blockIdx.x * 64;   // b
    int col0 = blockIdx.y * 64;   // a
    int lr = tid >> 2;
    int lk = (tid & 3) * 4;
    const float* pa = Hm + (size_t)(row0 + lr) * H_ + lk;
    const float* pb = W2 + (size_t)(col0 + lr) * H_ + lk;
    float acc[4][4] = {};
    for (int kt = 0; kt < H_; kt += 16) {
        float4 av = *reinterpret_cast<const float4*>(pa + kt);
        float4 bv = *reinterpret_cast<const float4*>(pb + kt);
        __syncthreads();
        As[lr][lk] = av.x; As[lr][lk + 1] = av.y; As[lr][lk + 2] = av.z; As[lr][lk + 3] = av.w;
        Bs[lr][lk] = bv.x; Bs[lr][lk + 1] = bv.y; Bs[lr][lk + 2] = bv.z; Bs[lr][lk + 3] = bv.w;
        __syncthreads();
        #pragma unroll
        for (int kk = 0; kk < 16; ++kk) {
            float a0 = As[ty * 4 + 0][kk], a1 = As[ty * 4 + 1][kk];
            float a2 = As[ty * 4 + 2][kk], a3 = As[ty * 4 + 3][kk];
            float b0 = Bs[tx * 4 + 0][kk], b1 = Bs[tx * 4 + 1][kk];
            float b2_ = Bs[tx * 4 + 2][kk], b3 = Bs[tx * 4 + 3][kk];
            acc[0][0] += a0 * b0; acc[0][1] += a0 * b1; acc[0][2] += a0 * b2_; acc[0][3] += a0 * b3;
            acc[1][0] += a1 * b0; acc[1][1] += a1 * b1; acc[1][2] += a1 * b2_; acc[1][3] += a1 * b3;
            acc[2][0] += a2 * b0; acc[2][1] += a2 * b1; acc[2][2] += a2 * b2_; acc[2][3] += a2 * b3;
            acc[3][0] += a3 * b0; acc[3][1] += a3 * b1; acc[3][2] += a3 * b2_; acc[3][3] += a3 * b3;
        }
    }
    int col = col0 + tx * 4;
    float4 bias2 = ld4(b2 + col);
    float* p = da + (size_t)(row0 + ty * 4) * A_ + col;
    #pragma unroll
    for (int i2 = 0; i2 < 4; ++i2) {
        float4 v = make_float4(acc[i2][0] + bias2.x, acc[i2][1] + bias2.y,
                               acc[i2][2] + bias2.z, acc[i2][3] + bias2.w);
        st4(p + (size_t)i2 * A_, v);
    }
}

// scatter: logits[b, idx[a]] += alpha * da[b,a], duplicates pre-summed along chain.
// Only the chain head writes -> each (b,l) written by exactly one thread.
__global__ void scatter_add(const float* __restrict__ da, const int* __restrict__ idx,
                            const int* __restrict__ head, const int* __restrict__ next,
                            const float* __restrict__ log_alpha,
                            float* __restrict__ logits) {
    int t = blockIdx.x * blockDim.x + threadIdx.x;
    if (t >= B_ * A_) return;
    int a = t & (A_ - 1);
    int b = t >> 12;
    int l = idx[a];
    if (head[l] != a) return;   // only chain heads act
    float alpha = 0.1f / (1.0f + expf(-log_alpha[0]));
    float s = 0.0f;
    for (int aa = a; aa >= 0; aa = next[aa]) s += da[(size_t)b * A_ + aa];
    logits[(size_t)b * L_ + l] += alpha * s;
}

static inline size_t align256(size_t x) { return (x + 255) & ~(size_t)255; }

extern "C" void kernel_launch(void* const* d_in, const int* in_sizes, int n_in,
                              void* d_out, int out_size, void* d_ws, size_t ws_size,
                              hipStream_t stream) {
    const float* x    = (const float*)d_in[0];
    const int*   idx  = (const int*)d_in[1];
    const float* gl   = (const float*)d_in[2];
    const float* dw   = (const float*)d_in[3];
    const float* bias = (const float*)d_in[4];
    const float* la   = (const float*)d_in[5];
    const float* hw   = (const float*)d_in[6];
    const float* hb   = (const float*)d_in[7];
    const float* w2   = (const float*)d_in[8];
    const float* b2   = (const float*)d_in[9];
    float* logits = (float*)d_out;

    char* ws = (char*)d_ws;
    int* head = (int*)ws;            ws += align256((size_t)L_ * 4);
    int* next = (int*)ws;            ws += align256((size_t)A_ * 4);
    float* xa = (float*)ws;          ws += align256((size_t)B_ * MA_ * 4);
    float* part = (float*)ws;        ws += align256((size_t)NZ_ * B_ * H_ * 4);
    float* h = (float*)ws;           ws += align256((size_t)B_ * H_ * 4);
    float* da = (float*)ws;          ws += align256((size_t)B_ * A_ * 4);

    init_head<<<(L_ + 255) / 256, 256, 0, stream>>>(head);
    build_chain<<<(A_ + 255) / 256, 256, 0, stream>>>(idx, head, next);

    dim3 g1((L_ / 4 + 255) / 256, B_ / BCHUNK_);
    logits_gather<<<g1, 256, 0, stream>>>(x, gl, dw, bias, head, next, logits, xa);

    gemm1_splitk<<<dim3(B_ / 64, H_ / 64, NZ_), 256, 0, stream>>>(xa, hw, part);
    reduce_relu<<<(B_ * H_ + 255) / 256, 256, 0, stream>>>(part, hb, h);
    gemm2<<<dim3(B_ / 64, A_ / 64), 256, 0, stream>>>(h, w2, b2, da);
    scatter_add<<<(B_ * A_ + 255) / 256, 256, 0, stream>>>(da, idx, head, next, la, logits);
}

// Round 2
// 202.698 us; speedup vs baseline: 1.8949x; 1.8949x over previous
//
#include <hip/hip_runtime.h>
#include <math.h>

#define B_ 256
#define M_ 3
#define L_ 100000
#define A_ 4096
#define H_ 512
#define MA_ (M_*A_)          // 12288 = K for GEMM1
#define K1_ MA_
#define NZ_ 16               // split-K chunks for GEMM1
#define KC1_ (K1_/NZ_)       // 768
#define BCHUNK_ 4

typedef __attribute__((ext_vector_type(8))) short bf16x8;
typedef __attribute__((ext_vector_type(8))) unsigned short u16x8;
typedef __attribute__((ext_vector_type(4))) float f32x4;

static __device__ __forceinline__ float4 ld4(const float* p) {
    return *reinterpret_cast<const float4*>(p);
}
static __device__ __forceinline__ void st4(float* p, float4 v) {
    *reinterpret_cast<float4*>(p) = v;
}
static __device__ __forceinline__ unsigned short f2bf(float f) {
    unsigned u = __float_as_uint(f);
    unsigned r = (u + 0x7FFFu + ((u >> 16) & 1u)) >> 16;
    return (unsigned short)r;
}
static __device__ __forceinline__ float getc(const float4& v, int c) {
    switch (c) { case 0: return v.x; case 1: return v.y; case 2: return v.z; default: return v.w; }
}

__global__ void init_head(int* __restrict__ head) {
    int i = blockIdx.x * blockDim.x + threadIdx.x;
    if (i < L_) head[i] = -1;
}

__global__ void build_chain(const int* __restrict__ idx, int* __restrict__ head,
                            int* __restrict__ next) {
    int a = blockIdx.x * blockDim.x + threadIdx.x;
    if (a < A_) next[a] = atomicExch(&head[idx[a]], a);
}

__global__ void f32_to_bf16(const float* __restrict__ in, unsigned short* __restrict__ out, int n8) {
    int i = blockIdx.x * blockDim.x + threadIdx.x;
    if (i >= n8) return;
    float4 v0 = ld4(in + (size_t)i * 8);
    float4 v1 = ld4(in + (size_t)i * 8 + 4);
    u16x8 o;
    o[0] = f2bf(v0.x); o[1] = f2bf(v0.y); o[2] = f2bf(v0.z); o[3] = f2bf(v0.w);
    o[4] = f2bf(v1.x); o[5] = f2bf(v1.y); o[6] = f2bf(v1.z); o[7] = f2bf(v1.w);
    *reinterpret_cast<u16x8*>(out + (size_t)i * 8) = o;
}

// Fused: logits[b,l] = sum_m x[b,m,l]*(softmax(gl)[m]+dw[m,l]) + bias[l]
// + gather x_active[b, m*A+a] = bf16(x[b,m,idx[a]]) via head/next chain map.
// BCHUNK=4 fully unrolled -> 12 independent float4 loads in flight.
__global__ __launch_bounds__(256) void logits_gather(
    const float* __restrict__ x, const float* __restrict__ gl,
    const float* __restrict__ dw, const float* __restrict__ bias,
    const int* __restrict__ head, const int* __restrict__ next,
    float* __restrict__ logits, unsigned short* __restrict__ xa) {
    const int L4 = L_ / 4;
    int i = blockIdx.x * blockDim.x + threadIdx.x;
    if (i >= L4) return;
    int l = i * 4;
    int b0 = blockIdx.y * BCHUNK_;

    float g0 = gl[0], g1 = gl[1], g2 = gl[2];
    float mx = fmaxf(g0, fmaxf(g1, g2));
    float e0 = expf(g0 - mx), e1 = expf(g1 - mx), e2 = expf(g2 - mx);
    float inv = 1.0f / (e0 + e1 + e2);
    float s0 = e0 * inv, s1 = e1 * inv, s2 = e2 * inv;

    float4 d0 = ld4(dw + l);
    float4 d1 = ld4(dw + L_ + l);
    float4 d2 = ld4(dw + 2 * L_ + l);
    float4 bb = ld4(bias + l);
    float4 w0 = make_float4(s0 + d0.x, s0 + d0.y, s0 + d0.z, s0 + d0.w);
    float4 w1 = make_float4(s1 + d1.x, s1 + d1.y, s1 + d1.z, s1 + d1.w);
    float4 w2 = make_float4(s2 + d2.x, s2 + d2.y, s2 + d2.z, s2 + d2.w);

    float4 X[BCHUNK_][3];
    #pragma unroll
    for (int c = 0; c < BCHUNK_; ++c) {
        const float* xb = x + (size_t)(b0 + c) * M_ * L_ + l;
        X[c][0] = ld4(xb);
        X[c][1] = ld4(xb + L_);
        X[c][2] = ld4(xb + 2 * L_);
    }
    #pragma unroll
    for (int c = 0; c < BCHUNK_; ++c) {
        float4 o;
        o.x = X[c][0].x * w0.x + X[c][1].x * w1.x + X[c][2].x * w2.x + bb.x;
        o.y = X[c][0].y * w0.y + X[c][1].y * w1.y + X[c][2].y * w2.y + bb.y;
        o.z = X[c][0].z * w0.z + X[c][1].z * w1.z + X[c][2].z * w2.z + bb.z;
        o.w = X[c][0].w * w0.w + X[c][1].w * w1.w + X[c][2].w * w2.w + bb.w;
        st4(logits + (size_t)(b0 + c) * L_ + l, o);
    }

    // gather (rare: ~4% of labels active)
    #pragma unroll
    for (int c = 0; c < 4; ++c) {
        int a = head[l + c];
        while (a >= 0) {
            #pragma unroll
            for (int b = 0; b < BCHUNK_; ++b) {
                unsigned short* xab = xa + (size_t)(b0 + b) * MA_;
                xab[a]            = f2bf(getc(X[b][0], c));
                xab[A_ + a]       = f2bf(getc(X[b][1], c));
                xab[2 * A_ + a]   = f2bf(getc(X[b][2], c));
            }
            a = next[a];
        }
    }
}

// GEMM1 split-K MFMA: part[z,b,n] = sum_{k in chunk z} xa[b,k] * hw[n,k]
// 4 waves/block, each wave a 32x32 output tile via 2x2 mfma_f32_16x16x32_bf16.
__global__ __launch_bounds__(256) void gemm1_mfma(
    const unsigned short* __restrict__ Xa, const unsigned short* __restrict__ W,
    float* __restrict__ part) {
    int tid = threadIdx.x;
    int wave = tid >> 6, lane = tid & 63;
    int row0 = blockIdx.x * 64 + (wave >> 1) * 32;
    int col0 = blockIdx.y * 64 + (wave & 1) * 32;
    int k0 = blockIdx.z * KC1_;
    int lr = lane & 15;
    int lk = (lane >> 4) * 8;
    const unsigned short* pa0 = Xa + (size_t)(row0 + lr) * K1_ + k0 + lk;
    const unsigned short* pa1 = pa0 + (size_t)16 * K1_;
    const unsigned short* pb0 = W + (size_t)(col0 + lr) * K1_ + k0 + lk;
    const unsigned short* pb1 = pb0 + (size_t)16 * K1_;
    f32x4 acc00 = {0.f,0.f,0.f,0.f}, acc01 = {0.f,0.f,0.f,0.f};
    f32x4 acc10 = {0.f,0.f,0.f,0.f}, acc11 = {0.f,0.f,0.f,0.f};
    #pragma unroll 4
    for (int k = 0; k < KC1_; k += 32) {
        bf16x8 a0 = *reinterpret_cast<const bf16x8*>(pa0 + k);
        bf16x8 a1 = *reinterpret_cast<const bf16x8*>(pa1 + k);
        bf16x8 b0 = *reinterpret_cast<const bf16x8*>(pb0 + k);
        bf16x8 b1 = *reinterpret_cast<const bf16x8*>(pb1 + k);
        acc00 = __builtin_amdgcn_mfma_f32_16x16x32_bf16(a0, b0, acc00, 0, 0, 0);
        acc01 = __builtin_amdgcn_mfma_f32_16x16x32_bf16(a0, b1, acc01, 0, 0, 0);
        acc10 = __builtin_amdgcn_mfma_f32_16x16x32_bf16(a1, b0, acc10, 0, 0, 0);
        acc11 = __builtin_amdgcn_mfma_f32_16x16x32_bf16(a1, b1, acc11, 0, 0, 0);
    }
    float* base = part + (size_t)blockIdx.z * B_ * H_;
    #pragma unroll
    for (int j = 0; j < 4; ++j) {
        int r = (lane >> 4) * 4 + j;   // C/D: col=lane&15, row=(lane>>4)*4+j  [m89-verified]
        base[(size_t)(row0 + r) * H_ + col0 + lr]           = acc00[j];
        base[(size_t)(row0 + r) * H_ + col0 + 16 + lr]      = acc01[j];
        base[(size_t)(row0 + 16 + r) * H_ + col0 + lr]      = acc10[j];
        base[(size_t)(row0 + 16 + r) * H_ + col0 + 16 + lr] = acc11[j];
    }
}

// h[b,n] = bf16(relu(sum_z part[z,b,n] + hb[n]))
__global__ void reduce_relu(const float* __restrict__ part,
                            const float* __restrict__ hb,
                            unsigned short* __restrict__ h) {
    int t = blockIdx.x * blockDim.x + threadIdx.x;
    if (t >= B_ * H_) return;
    int n = t & (H_ - 1);
    float s = hb[n];
    #pragma unroll
    for (int z = 0; z < NZ_; ++z) s += part[(size_t)z * B_ * H_ + t];
    h[t] = f2bf(fmaxf(s, 0.0f));
}

// GEMM2 MFMA: da[b,a] = alpha * (sum_n h[b,n]*W2[a,n] + b2[a])   (K = 512)
__global__ __launch_bounds__(256) void gemm2_mfma(
    const unsigned short* __restrict__ Hm, const unsigned short* __restrict__ W2,
    const float* __restrict__ b2, const float* __restrict__ la,
    float* __restrict__ da) {
    int tid = threadIdx.x;
    int wave = tid >> 6, lane = tid & 63;
    int row0 = blockIdx.x * 64 + (wave >> 1) * 32;
    int col0 = blockIdx.y * 64 + (wave & 1) * 32;
    int lr = lane & 15;
    int lk = (lane >> 4) * 8;
    const unsigned short* pa0 = Hm + (size_t)(row0 + lr) * H_ + lk;
    const unsigned short* pa1 = pa0 + (size_t)16 * H_;
    const unsigned short* pb0 = W2 + (size_t)(col0 + lr) * H_ + lk;
    const unsigned short* pb1 = pb0 + (size_t)16 * H_;
    f32x4 acc00 = {0.f,0.f,0.f,0.f}, acc01 = {0.f,0.f,0.f,0.f};
    f32x4 acc10 = {0.f,0.f,0.f,0.f}, acc11 = {0.f,0.f,0.f,0.f};
    #pragma unroll 4
    for (int k = 0; k < H_; k += 32) {
        bf16x8 a0 = *reinterpret_cast<const bf16x8*>(pa0 + k);
        bf16x8 a1 = *reinterpret_cast<const bf16x8*>(pa1 + k);
        bf16x8 b0 = *reinterpret_cast<const bf16x8*>(pb0 + k);
        bf16x8 b1 = *reinterpret_cast<const bf16x8*>(pb1 + k);
        acc00 = __builtin_amdgcn_mfma_f32_16x16x32_bf16(a0, b0, acc00, 0, 0, 0);
        acc01 = __builtin_amdgcn_mfma_f32_16x16x32_bf16(a0, b1, acc01, 0, 0, 0);
        acc10 = __builtin_amdgcn_mfma_f32_16x16x32_bf16(a1, b0, acc10, 0, 0, 0);
        acc11 = __builtin_amdgcn_mfma_f32_16x16x32_bf16(a1, b1, acc11, 0, 0, 0);
    }
    float alpha = 0.1f / (1.0f + expf(-la[0]));
    #pragma unroll
    for (int j = 0; j < 4; ++j) {
        int r = (lane >> 4) * 4 + j;
        int c0 = col0 + lr, c1 = col0 + 16 + lr;
        da[(size_t)(row0 + r) * A_ + c0]      = alpha * (acc00[j] + b2[c0]);
        da[(size_t)(row0 + r) * A_ + c1]      = alpha * (acc01[j] + b2[c1]);
        da[(size_t)(row0 + 16 + r) * A_ + c0] = alpha * (acc10[j] + b2[c0]);
        da[(size_t)(row0 + 16 + r) * A_ + c1] = alpha * (acc11[j] + b2[c1]);
    }
}

// scatter: logits[b, idx[a]] += da[b,a] (already alpha-scaled), chain-deduped.
__global__ void scatter_add(const float* __restrict__ da, const int* __restrict__ idx,
                            const int* __restrict__ head, const int* __restrict__ next,
                            float* __restrict__ logits) {
    int t = blockIdx.x * blockDim.x + threadIdx.x;
    if (t >= B_ * A_) return;
    int a = t & (A_ - 1);
    int b = t >> 12;
    int l = idx[a];
    if (head[l] != a) return;
    float s = 0.0f;
    for (int aa = a; aa >= 0; aa = next[aa]) s += da[(size_t)b * A_ + aa];
    logits[(size_t)b * L_ + l] += s;
}

static inline size_t align256(size_t x) { return (x + 255) & ~(size_t)255; }

extern "C" void kernel_launch(void* const* d_in, const int* in_sizes, int n_in,
                              void* d_out, int out_size, void* d_ws, size_t ws_size,
                              hipStream_t stream) {
    const float* x    = (const float*)d_in[0];
    const int*   idx  = (const int*)d_in[1];
    const float* gl   = (const float*)d_in[2];
    const float* dw   = (const float*)d_in[3];
    const float* bias = (const float*)d_in[4];
    const float* la   = (const float*)d_in[5];
    const float* hw   = (const float*)d_in[6];
    const float* hb   = (const float*)d_in[7];
    const float* w2   = (const float*)d_in[8];
    const float* b2   = (const float*)d_in[9];
    float* logits = (float*)d_out;

    char* ws = (char*)d_ws;
    int* head = (int*)ws;              ws += align256((size_t)L_ * 4);
    int* next = (int*)ws;              ws += align256((size_t)A_ * 4);
    unsigned short* xa = (unsigned short*)ws;   ws += align256((size_t)B_ * MA_ * 2);
    unsigned short* hwb = (unsigned short*)ws;  ws += align256((size_t)H_ * MA_ * 2);
    unsigned short* w2b = (unsigned short*)ws;  ws += align256((size_t)A_ * H_ * 2);
    float* part = (float*)ws;          ws += align256((size_t)NZ_ * B_ * H_ * 4);
    unsigned short* h = (unsigned short*)ws;    ws += align256((size_t)B_ * H_ * 2);
    float* da = part;                  // alias: part consumed by reduce_relu before gemm2 writes da

    init_head<<<(L_ + 255) / 256, 256, 0, stream>>>(head);
    build_chain<<<(A_ + 255) / 256, 256, 0, stream>>>(idx, head, next);

    f32_to_bf16<<<(H_ * MA_ / 8 + 255) / 256, 256, 0, stream>>>(hw, hwb, H_ * MA_ / 8);
    f32_to_bf16<<<(A_ * H_ / 8 + 255) / 256, 256, 0, stream>>>(w2, w2b, A_ * H_ / 8);

    dim3 g1((L_ / 4 + 255) / 256, B_ / BCHUNK_);
    logits_gather<<<g1, 256, 0, stream>>>(x, gl, dw, bias, head, next, logits, xa);

    gemm1_mfma<<<dim3(B_ / 64, H_ / 64, NZ_), 256, 0, stream>>>(xa, hwb, part);
    reduce_relu<<<(B_ * H_ + 255) / 256, 256, 0, stream>>>(part, hb, h);
    gemm2_mfma<<<dim3(B_ / 64, A_ / 64), 256, 0, stream>>>(h, w2b, b2, la, da);
    scatter_add<<<(B_ * A_ + 255) / 256, 256, 0, stream>>>(da, idx, head, next, logits);
}